// Round 14
// baseline (71.502 us; speedup 1.0000x reference)
//
#include <hip/hip_runtime.h>
#include <math.h>

#define LL 768
#define CT 64
#define KD 192
#define OC 1024
#define TS 16
#define NST 48           // 768/16 tiles per dim
#define PCH 68           // partial line: 64 ch + z at [64], padded to 68

// 16-lane-group sum via DPP: quad_perm(xor1), quad_perm(xor2), row_ror:4,
// row_ror:8 — pure VALU, no DS ops. On-device verified (R6/R9).
__device__ __forceinline__ float sum16(float x) {
    x += __int_as_float(__builtin_amdgcn_update_dpp(0, __float_as_int(x), 0xB1, 0xF, 0xF, true));
    x += __int_as_float(__builtin_amdgcn_update_dpp(0, __float_as_int(x), 0x4E, 0xF, 0xF, true));
    x += __int_as_float(__builtin_amdgcn_update_dpp(0, __float_as_int(x), 0x124, 0xF, 0xF, true));
    x += __int_as_float(__builtin_amdgcn_update_dpp(0, __float_as_int(x), 0x128, 0xF, 0xF, true));
    return x;
}

// ---------------- K1: fused logits+exp+row/col sums, 1 feat pass ----------------
// R13 body with ONE change: 4-deep static prefetch ring (fr0..fr3) keeps 4
// independent 1KB wave-loads in flight (R13's fnext = depth 1). launch_bounds
// (256,4) matches the 4-blocks/CU LDS cap and budgets 128 VGPR for the ring.
__global__ __launch_bounds__(256, 4) void k_fused(const float* __restrict__ feat,
                                                  const float* __restrict__ Wq,
                                                  const float* __restrict__ bq,
                                                  float* __restrict__ rp,
                                                  float* __restrict__ cp) {
    __shared__ float4 lbuf[16][8][17];   // [u][ii][c4 pad 17]
    __shared__ float  zb[16][9];         // per-(u, ii) row-z contribution

    int t = threadIdx.x;
    int u = t >> 4, q = t & 15;
    int bj = blockIdx.x, bi = blockIdx.y;   // bj fast (R12 mapping, neutral)
    int i0 = bi * TS, j0 = bj * TS;

    const float4 wq = *reinterpret_cast<const float4*>(Wq + q * 4);
    const float bqv = bq[0];

    const float* fb = feat + ((size_t)i0 * LL + j0 + u) * CT + q * 4;
    const size_t istr = (size_t)LL * CT;
    float4 creg = make_float4(0.f, 0.f, 0.f, 0.f);
    float zc = 0.f;

    // prefetch ring, depth 4: steady state has 4 loads in flight
    float4 fr0 = *reinterpret_cast<const float4*>(fb + 0 * istr);
    float4 fr1 = *reinterpret_cast<const float4*>(fb + 1 * istr);
    float4 fr2 = *reinterpret_cast<const float4*>(fb + 2 * istr);
    float4 fr3 = *reinterpret_cast<const float4*>(fb + 3 * istr);

    #pragma unroll
    for (int half = 0; half < 2; ++half) {
        #pragma unroll
        for (int ii = 0; ii < 8; ++ii) {
            const int idx = half * 8 + ii;
            float4 f;
            if ((idx & 3) == 0)      { f = fr0; if (idx + 4 < 16) fr0 = *reinterpret_cast<const float4*>(fb + (size_t)(idx + 4) * istr); }
            else if ((idx & 3) == 1) { f = fr1; if (idx + 4 < 16) fr1 = *reinterpret_cast<const float4*>(fb + (size_t)(idx + 4) * istr); }
            else if ((idx & 3) == 2) { f = fr2; if (idx + 4 < 16) fr2 = *reinterpret_cast<const float4*>(fb + (size_t)(idx + 4) * istr); }
            else                     { f = fr3; if (idx + 4 < 16) fr3 = *reinterpret_cast<const float4*>(fb + (size_t)(idx + 4) * istr); }

            float s = f.x * wq.x + f.y * wq.y + f.z * wq.z + f.w * wq.w;
            s = sum16(s);                    // DPP, pure VALU
            float e = __expf(s + bqv);

            float4 p;
            p.x = e * f.x; p.y = e * f.y; p.z = e * f.z; p.w = e * f.w;

            // col accumulation (register)
            creg.x += p.x; creg.y += p.y; creg.z += p.z; creg.w += p.w;
            zc += e;

            // row contribution: one LDS write (assignment, no RMW)
            lbuf[u][ii][q] = p;
            if (q == 0) zb[u][ii] = e;
        }
        __syncthreads();

        // fold row partials over the 16 u-columns -> rp[line][strip=bj][*]
        if (t < 128) {
            int ii = t >> 4, c4 = t & 15;
            float4 a = make_float4(0.f, 0.f, 0.f, 0.f);
            #pragma unroll
            for (int uu = 0; uu < 16; ++uu) {
                const float4 v = lbuf[uu][ii][c4];
                a.x += v.x; a.y += v.y; a.z += v.z; a.w += v.w;
            }
            *reinterpret_cast<float4*>(rp + ((size_t)(i0 + half * 8 + ii) * NST + bj) * PCH
                                       + c4 * 4) = a;
        }
        if (t < 8) {
            float zz = 0.f;
            #pragma unroll
            for (int uu = 0; uu < 16; ++uu) zz += zb[uu][t];
            rp[((size_t)(i0 + half * 8 + t) * NST + bj) * PCH + 64] = zz;
        }
        __syncthreads();
    }

    // col partials out -> cp[line=j][strip=bi][*]
    size_t cpo = ((size_t)(j0 + u) * NST + bi) * PCH;
    *reinterpret_cast<float4*>(cp + cpo + q * 4) = creg;
    if (q == 0) cp[cpo + 64] = zc;
}

// ---------------- K2: fold 48 strip-partials (line-major), /z -> rcfeat -------
__global__ __launch_bounds__(256) void k_combine(const float* __restrict__ rp,
                                                 const float* __restrict__ cp,
                                                 float* __restrict__ rcfeat) {
    int t = threadIdx.x;
    int r = t >> 4, q = t & 15;
    int L = blockIdx.x * 16 + r;
    int side = blockIdx.y;
    const float* base = (side ? cp : rp) + (size_t)L * NST * PCH;

    float4 acc = make_float4(0.f, 0.f, 0.f, 0.f);
    float z = 0.f;
    #pragma unroll 4
    for (int s = 0; s < NST; ++s) {
        const float4 v = *reinterpret_cast<const float4*>(base + s * PCH + q * 4);
        acc.x += v.x; acc.y += v.y; acc.z += v.z; acc.w += v.w;
        z += base[s * PCH + 64];
    }
    float inv = 1.0f / z;
    acc.x *= inv; acc.y *= inv; acc.z *= inv; acc.w *= inv;
    *reinterpret_cast<float4*>(rcfeat + (size_t)side * LL * CT
                               + (size_t)L * CT + q * 4) = acc;
}

// ---------------- K3: diag gather + LN + (x @ W + b) [*sigma] ----------------
__global__ __launch_bounds__(256) void k_final(const float* __restrict__ feat,
                                               const float* __restrict__ rcfeat,
                                               const float* __restrict__ ln_g,
                                               const float* __restrict__ ln_b,
                                               const float* __restrict__ WU,
                                               const float* __restrict__ bU,
                                               const float* __restrict__ WV,
                                               const float* __restrict__ bV,
                                               const float* __restrict__ sigma,
                                               float* __restrict__ out) {
    __shared__ float xbuf[8][KD];
    int t = threadIdx.x;
    int wid = t >> 6, l = t & 63;
    int r0 = blockIdx.x * 8;
    int right = blockIdx.y;
    const float* rfeat = rcfeat;
    const float* cfeat = rcfeat + LL * CT;

    for (int r = wid; r < 8; r += 4) {
        int i = r0 + r;
        float d  = feat[((size_t)i * LL + i) * CT + l];
        float rv = rfeat[(size_t)i * CT + l];
        float cv = cfeat[(size_t)i * CT + l];
        float sum = d + rv + cv;
        #pragma unroll
        for (int o = 32; o; o >>= 1) sum += __shfl_xor(sum, o);
        float mu = sum * (1.0f / 192.0f);
        float d0 = d - mu, d1 = rv - mu, d2 = cv - mu;
        float sq = d0 * d0 + d1 * d1 + d2 * d2;
        #pragma unroll
        for (int o = 32; o; o >>= 1) sq += __shfl_xor(sq, o);
        float rstd = rsqrtf(sq * (1.0f / 192.0f) + 1e-5f);
        float h0 = d0 * rstd, h1 = d1 * rstd, h2 = d2 * rstd;
        float a1 = right ? h2 : h1;
        float a2 = right ? h1 : h2;
        xbuf[r][l]       = h0 * ln_g[l]       + ln_b[l];
        xbuf[r][64 + l]  = a1 * ln_g[64 + l]  + ln_b[64 + l];
        xbuf[r][128 + l] = a2 * ln_g[128 + l] + ln_b[128 + l];
    }
    __syncthreads();

    const float* W    = right ? WV : WU;
    const float* bias = right ? bV : bU;
    int o = blockIdx.z * 512 + t * 2;       // 2 columns per thread
    float2 acc[8];
    #pragma unroll
    for (int r = 0; r < 8; ++r) acc[r] = make_float2(0.f, 0.f);

    for (int k = 0; k < KD; k += 4) {
        float4 xr[8];
        #pragma unroll
        for (int r = 0; r < 8; ++r)
            xr[r] = *reinterpret_cast<const float4*>(&xbuf[r][k]);
        #pragma unroll
        for (int kk = 0; kk < 4; ++kk) {
            const float2 wv = *reinterpret_cast<const float2*>(W + (size_t)(k + kk) * OC + o);
            #pragma unroll
            for (int r = 0; r < 8; ++r) {
                float xv = (&xr[r].x)[kk];
                acc[r].x = fmaf(xv, wv.x, acc[r].x);
                acc[r].y = fmaf(xv, wv.y, acc[r].y);
            }
        }
    }

    const float2 bb = *reinterpret_cast<const float2*>(bias + o);
    float sg = right ? 1.0f : sigma[o >> 7];
    float* obase = out + (right ? (size_t)LL * OC : 0);
    #pragma unroll
    for (int r = 0; r < 8; ++r) {
        float2 v;
        v.x = (acc[r].x + bb.x) * sg;
        v.y = (acc[r].y + bb.y) * sg;
        *reinterpret_cast<float2*>(obase + (size_t)(r0 + r) * OC + o) = v;
    }
}

extern "C" void kernel_launch(void* const* d_in, const int* in_sizes, int n_in,
                              void* d_out, int out_size, void* d_ws, size_t ws_size,
                              hipStream_t stream) {
    const float* feat  = (const float*)d_in[0];
    const float* Wq    = (const float*)d_in[1];
    const float* bq    = (const float*)d_in[2];
    const float* ln_g  = (const float*)d_in[3];
    const float* ln_b  = (const float*)d_in[4];
    const float* WU    = (const float*)d_in[5];
    const float* bU    = (const float*)d_in[6];
    const float* WV    = (const float*)d_in[7];
    const float* bV    = (const float*)d_in[8];
    const float* sigma = (const float*)d_in[9];
    float* out = (float*)d_out;

    float* ws     = (float*)d_ws;
    float* rp     = ws;                                  // LL*NST*PCH
    float* cp     = rp + (size_t)LL * NST * PCH;         // LL*NST*PCH
    float* rcfeat = cp + (size_t)LL * NST * PCH;         // 2*LL*CT

    hipLaunchKernelGGL(k_fused, dim3(NST, NST), dim3(256), 0, stream,
                       feat, Wq, bq, rp, cp);
    hipLaunchKernelGGL(k_combine, dim3(LL / 16, 2), dim3(256), 0, stream,
                       rp, cp, rcfeat);
    hipLaunchKernelGGL(k_final, dim3(LL / 8, 2, 2), dim3(256), 0, stream,
                       feat, rcfeat, ln_g, ln_b, WU, bU, WV, bV, sigma, out);
}

// Round 15
// 61.279 us; speedup vs baseline: 1.1668x; 1.1668x over previous
//
#include <hip/hip_runtime.h>
#include <math.h>

#define LL 768
#define CT 64
#define KD 192
#define OC 1024
#define TS 16
#define NST 48           // 768/16 tiles per dim
#define PCH 68           // partial line: 64 ch + z at [64]

// 16-lane-group sum via DPP: quad_perm(xor1), quad_perm(xor2), row_ror:4,
// row_ror:8 — pure VALU. On-device verified (R6/R9).
__device__ __forceinline__ float sum16(float x) {
    x += __int_as_float(__builtin_amdgcn_update_dpp(0, __float_as_int(x), 0xB1, 0xF, 0xF, true));
    x += __int_as_float(__builtin_amdgcn_update_dpp(0, __float_as_int(x), 0x4E, 0xF, 0xF, true));
    x += __int_as_float(__builtin_amdgcn_update_dpp(0, __float_as_int(x), 0x124, 0xF, 0xF, true));
    x += __int_as_float(__builtin_amdgcn_update_dpp(0, __float_as_int(x), 0x128, 0xF, 0xF, true));
    return x;
}

// ---------------- K1: fused pass, wave-owned rows, ONE barrier per tile --------
// Block = 16x16 tile. Wave w owns rows i0+4w..4w+3 ENTIRELY (row sums are
// wave-local; no mid-tile __syncthreads -> the 16 independent 1KB loads are
// never vmcnt(0)-drained mid-stream). Lane (g=ln>>4, q=ln&15): col j0+jb*4+g,
// channel quad q. Col partials in static registers; single LDS fold+barrier
// at tile end. rp/cp line-major as in R13.
__global__ __launch_bounds__(256) void k_fused(const float* __restrict__ feat,
                                               const float* __restrict__ Wq,
                                               const float* __restrict__ bq,
                                               float* __restrict__ rp,
                                               float* __restrict__ cp) {
    __shared__ float cpart[4][16][68];   // [wave][j-in-tile][64ch + z]

    int t = threadIdx.x;
    int w = t >> 6, ln = t & 63;
    int g = ln >> 4, q = ln & 15;
    int bj = blockIdx.x, bi = blockIdx.y;   // bj fast (R12 mapping)
    int i0 = bi * TS, j0 = bj * TS;

    const float4 wq = *reinterpret_cast<const float4*>(Wq + q * 4);
    const float bqv = bq[0];

    float4 c0 = make_float4(0,0,0,0), c1 = make_float4(0,0,0,0);
    float4 c2 = make_float4(0,0,0,0), c3 = make_float4(0,0,0,0);
    float zc0 = 0.f, zc1 = 0.f, zc2 = 0.f, zc3 = 0.f;

    #define STEP(F, CR, ZC)                                              \
        {                                                                \
            float s = F.x * wq.x + F.y * wq.y + F.z * wq.z + F.w * wq.w; \
            s = sum16(s);                                                \
            float e = __expf(s + bqv);                                   \
            float4 p;                                                    \
            p.x = e * F.x; p.y = e * F.y; p.z = e * F.z; p.w = e * F.w;  \
            racc.x += p.x; racc.y += p.y; racc.z += p.z; racc.w += p.w;  \
            zr += e;                                                     \
            CR.x += p.x; CR.y += p.y; CR.z += p.z; CR.w += p.w;          \
            ZC += e;                                                     \
        }

    #pragma unroll
    for (int r = 0; r < 4; ++r) {
        const int row = i0 + w * 4 + r;
        const float* fb = feat + ((size_t)row * LL + j0 + g) * CT + q * 4;

        const float4 f0 = *reinterpret_cast<const float4*>(fb + 0 * 4 * CT);
        const float4 f1 = *reinterpret_cast<const float4*>(fb + 1 * 4 * CT);
        const float4 f2 = *reinterpret_cast<const float4*>(fb + 2 * 4 * CT);
        const float4 f3 = *reinterpret_cast<const float4*>(fb + 3 * 4 * CT);

        float4 racc = make_float4(0,0,0,0);
        float zr = 0.f;
        STEP(f0, c0, zc0)
        STEP(f1, c1, zc1)
        STEP(f2, c2, zc2)
        STEP(f3, c3, zc3)

        // row fold over the 4 j-groups (wave-local, register-only chain)
        racc.x += __shfl_xor(racc.x, 16); racc.x += __shfl_xor(racc.x, 32);
        racc.y += __shfl_xor(racc.y, 16); racc.y += __shfl_xor(racc.y, 32);
        racc.z += __shfl_xor(racc.z, 16); racc.z += __shfl_xor(racc.z, 32);
        racc.w += __shfl_xor(racc.w, 16); racc.w += __shfl_xor(racc.w, 32);
        zr     += __shfl_xor(zr, 16);     zr     += __shfl_xor(zr, 32);

        if (g == 0) {
            size_t ro = ((size_t)row * NST + bj) * PCH;
            *reinterpret_cast<float4*>(rp + ro + q * 4) = racc;
            if (q == 0) rp[ro + 64] = zr;
        }
    }
    #undef STEP

    // col partials -> LDS (one write per jb), single barrier, cross-wave fold
    *reinterpret_cast<float4*>(&cpart[w][0 * 4 + g][q * 4]) = c0;
    *reinterpret_cast<float4*>(&cpart[w][1 * 4 + g][q * 4]) = c1;
    *reinterpret_cast<float4*>(&cpart[w][2 * 4 + g][q * 4]) = c2;
    *reinterpret_cast<float4*>(&cpart[w][3 * 4 + g][q * 4]) = c3;
    if (q == 0) {
        cpart[w][0 * 4 + g][64] = zc0;
        cpart[w][1 * 4 + g][64] = zc1;
        cpart[w][2 * 4 + g][64] = zc2;
        cpart[w][3 * 4 + g][64] = zc3;
    }
    __syncthreads();

    {
        int jj = t >> 4, c4 = t & 15;
        const float4 a0 = *reinterpret_cast<const float4*>(&cpart[0][jj][c4 * 4]);
        const float4 a1 = *reinterpret_cast<const float4*>(&cpart[1][jj][c4 * 4]);
        const float4 a2 = *reinterpret_cast<const float4*>(&cpart[2][jj][c4 * 4]);
        const float4 a3 = *reinterpret_cast<const float4*>(&cpart[3][jj][c4 * 4]);
        float4 a;
        a.x = (a0.x + a1.x) + (a2.x + a3.x);
        a.y = (a0.y + a1.y) + (a2.y + a3.y);
        a.z = (a0.z + a1.z) + (a2.z + a3.z);
        a.w = (a0.w + a1.w) + (a2.w + a3.w);
        size_t co = ((size_t)(j0 + jj) * NST + bi) * PCH;
        *reinterpret_cast<float4*>(cp + co + c4 * 4) = a;
        if (c4 == 0)
            cp[co + 64] = cpart[0][jj][64] + cpart[1][jj][64]
                        + cpart[2][jj][64] + cpart[3][jj][64];
    }
}

// ---------------- K2: fold 48 strip-partials (line-major), /z -> rcfeat -------
__global__ __launch_bounds__(256) void k_combine(const float* __restrict__ rp,
                                                 const float* __restrict__ cp,
                                                 float* __restrict__ rcfeat) {
    int t = threadIdx.x;
    int r = t >> 4, q = t & 15;
    int L = blockIdx.x * 16 + r;
    int side = blockIdx.y;
    const float* base = (side ? cp : rp) + (size_t)L * NST * PCH;

    float4 acc = make_float4(0.f, 0.f, 0.f, 0.f);
    float z = 0.f;
    #pragma unroll 4
    for (int s = 0; s < NST; ++s) {
        const float4 v = *reinterpret_cast<const float4*>(base + s * PCH + q * 4);
        acc.x += v.x; acc.y += v.y; acc.z += v.z; acc.w += v.w;
        z += base[s * PCH + 64];
    }
    float inv = 1.0f / z;
    acc.x *= inv; acc.y *= inv; acc.z *= inv; acc.w *= inv;
    *reinterpret_cast<float4*>(rcfeat + (size_t)side * LL * CT
                               + (size_t)L * CT + q * 4) = acc;
}

// ---------------- K3: diag gather + LN + (x @ W + b) [*sigma] ----------------
__global__ __launch_bounds__(256) void k_final(const float* __restrict__ feat,
                                               const float* __restrict__ rcfeat,
                                               const float* __restrict__ ln_g,
                                               const float* __restrict__ ln_b,
                                               const float* __restrict__ WU,
                                               const float* __restrict__ bU,
                                               const float* __restrict__ WV,
                                               const float* __restrict__ bV,
                                               const float* __restrict__ sigma,
                                               float* __restrict__ out) {
    __shared__ float xbuf[8][KD];
    int t = threadIdx.x;
    int wid = t >> 6, l = t & 63;
    int r0 = blockIdx.x * 8;
    int right = blockIdx.y;
    const float* rfeat = rcfeat;
    const float* cfeat = rcfeat + LL * CT;

    for (int r = wid; r < 8; r += 4) {
        int i = r0 + r;
        float d  = feat[((size_t)i * LL + i) * CT + l];
        float rv = rfeat[(size_t)i * CT + l];
        float cv = cfeat[(size_t)i * CT + l];
        float sum = d + rv + cv;
        #pragma unroll
        for (int o = 32; o; o >>= 1) sum += __shfl_xor(sum, o);
        float mu = sum * (1.0f / 192.0f);
        float d0 = d - mu, d1 = rv - mu, d2 = cv - mu;
        float sq = d0 * d0 + d1 * d1 + d2 * d2;
        #pragma unroll
        for (int o = 32; o; o >>= 1) sq += __shfl_xor(sq, o);
        float rstd = rsqrtf(sq * (1.0f / 192.0f) + 1e-5f);
        float h0 = d0 * rstd, h1 = d1 * rstd, h2 = d2 * rstd;
        float a1 = right ? h2 : h1;
        float a2 = right ? h1 : h2;
        xbuf[r][l]       = h0 * ln_g[l]       + ln_b[l];
        xbuf[r][64 + l]  = a1 * ln_g[64 + l]  + ln_b[64 + l];
        xbuf[r][128 + l] = a2 * ln_g[128 + l] + ln_b[128 + l];
    }
    __syncthreads();

    const float* W    = right ? WV : WU;
    const float* bias = right ? bV : bU;
    int o = blockIdx.z * 512 + t * 2;       // 2 columns per thread
    float2 acc[8];
    #pragma unroll
    for (int r = 0; r < 8; ++r) acc[r] = make_float2(0.f, 0.f);

    for (int k = 0; k < KD; k += 4) {
        float4 xr[8];
        #pragma unroll
        for (int r = 0; r < 8; ++r)
            xr[r] = *reinterpret_cast<const float4*>(&xbuf[r][k]);
        #pragma unroll
        for (int kk = 0; kk < 4; ++kk) {
            const float2 wv = *reinterpret_cast<const float2*>(W + (size_t)(k + kk) * OC + o);
            #pragma unroll
            for (int r = 0; r < 8; ++r) {
                float xv = (&xr[r].x)[kk];
                acc[r].x = fmaf(xv, wv.x, acc[r].x);
                acc[r].y = fmaf(xv, wv.y, acc[r].y);
            }
        }
    }

    const float2 bb = *reinterpret_cast<const float2*>(bias + o);
    float sg = right ? 1.0f : sigma[o >> 7];
    float* obase = out + (right ? (size_t)LL * OC : 0);
    #pragma unroll
    for (int r = 0; r < 8; ++r) {
        float2 v;
        v.x = (acc[r].x + bb.x) * sg;
        v.y = (acc[r].y + bb.y) * sg;
        *reinterpret_cast<float2*>(obase + (size_t)(r0 + r) * OC + o) = v;
    }
}

extern "C" void kernel_launch(void* const* d_in, const int* in_sizes, int n_in,
                              void* d_out, int out_size, void* d_ws, size_t ws_size,
                              hipStream_t stream) {
    const float* feat  = (const float*)d_in[0];
    const float* Wq    = (const float*)d_in[1];
    const float* bq    = (const float*)d_in[2];
    const float* ln_g  = (const float*)d_in[3];
    const float* ln_b  = (const float*)d_in[4];
    const float* WU    = (const float*)d_in[5];
    const float* bU    = (const float*)d_in[6];
    const float* WV    = (const float*)d_in[7];
    const float* bV    = (const float*)d_in[8];
    const float* sigma = (const float*)d_in[9];
    float* out = (float*)d_out;

    float* ws     = (float*)d_ws;
    float* rp     = ws;                                  // LL*NST*PCH
    float* cp     = rp + (size_t)LL * NST * PCH;         // LL*NST*PCH
    float* rcfeat = cp + (size_t)LL * NST * PCH;         // 2*LL*CT

    hipLaunchKernelGGL(k_fused, dim3(NST, NST), dim3(256), 0, stream,
                       feat, Wq, bq, rp, cp);
    hipLaunchKernelGGL(k_combine, dim3(LL / 16, 2), dim3(256), 0, stream,
                       rp, cp, rcfeat);
    hipLaunchKernelGGL(k_final, dim3(LL / 8, 2, 2), dim3(256), 0, stream,
                       feat, rcfeat, ln_g, ln_b, WU, bU, WV, bV, sigma, out);
}